// Round 2
// baseline (453.977 us; speedup 1.0000x reference)
//
#include <hip/hip_runtime.h>

// ---------------------------------------------------------------------------
// GraphSAGE 2-layer, mean aggregation.
//   L1: h = relu( mean_nbr(x) @ W_l1 + x @ W_r1 + b1 )   (IN=2 -> aggregate x first)
//   L2: out = mean_nbr(h) @ W_l2 + h @ W_r2 + b2
// Pipeline: count -> scan -> CSR fill -> agg1(x) -> h(bf16) -> Wt prep(bf16)
//           -> agg2(bf16, wave/node) -> MFMA GEMM (K=256 concat) -> out fp32
// R1 fix: k_agg2 output stride — a16 row is 64 uints (128 bf16), wrote with
//         stride 32 -> overlapping rows and k_gemm read node 2r's agg.
// ---------------------------------------------------------------------------

using f32x4 = __attribute__((ext_vector_type(4))) float;
using s16x8 = __attribute__((ext_vector_type(8))) short;

__device__ __forceinline__ unsigned short f32_to_bf16(float f) {
  unsigned int u = __float_as_uint(f);
  u += 0x7fffu + ((u >> 16) & 1u);          // round-to-nearest-even
  return (unsigned short)(u >> 16);
}
__device__ __forceinline__ float bf16lo(unsigned int p) { return __uint_as_float(p << 16); }
__device__ __forceinline__ float bf16hi(unsigned int p) { return __uint_as_float(p & 0xffff0000u); }

// ---- edge pass 1: degree count ----------------------------------------------
__global__ __launch_bounds__(256) void k_count(const int* __restrict__ ei, int* __restrict__ degi, int E) {
  int e = blockIdx.x * 256 + threadIdx.x;
  if (e < E) atomicAdd(&degi[ei[E + e]], 1);
}

// ---- scan step 1: per-block (1024 elems) local exclusive scan ---------------
__global__ __launch_bounds__(256) void k_scan1(const int* __restrict__ degi, int* __restrict__ loc,
                                               int* __restrict__ btot, int n) {
  __shared__ int sm[2][256];
  int t = threadIdx.x;
  int base = blockIdx.x * 1024 + t * 4;
  int d[4]; int s = 0;
#pragma unroll
  for (int j = 0; j < 4; ++j) { d[j] = (base + j < n) ? degi[base + j] : 0; s += d[j]; }
  sm[0][t] = s; __syncthreads();
  int src = 0;
  for (int st = 1; st < 256; st <<= 1) {
    int v = sm[src][t];
    if (t >= st) v += sm[src][t - st];
    sm[src ^ 1][t] = v; __syncthreads(); src ^= 1;
  }
  int incl = sm[src][t];
  int ex = incl - s;
#pragma unroll
  for (int j = 0; j < 4; ++j) { if (base + j < n) loc[base + j] = ex; ex += d[j]; }
  if (t == 255) btot[blockIdx.x] = incl;
}

// ---- scan step 2: scan the (<=128) block totals -----------------------------
__global__ __launch_bounds__(128) void k_scan2(const int* __restrict__ btot, int* __restrict__ bpre, int nb) {
  __shared__ int sm[128];
  int t = threadIdx.x;
  if (t < nb) sm[t] = btot[t];
  __syncthreads();
  if (t == 0) { int run = 0; for (int i = 0; i < nb; ++i) { int v = sm[i]; sm[i] = run; run += v; } }
  __syncthreads();
  if (t < nb) bpre[t] = sm[t];
}

// ---- scan step 3: add block prefixes; produce offsets + cursor copy ---------
__global__ __launch_bounds__(256) void k_scan3(int* __restrict__ offs, int* __restrict__ cursor,
                                               const int* __restrict__ bpre, int n, int total) {
  int i = blockIdx.x * 256 + threadIdx.x;
  if (i == 0) offs[n] = total;
  if (i < n) { int v = offs[i] + bpre[i >> 10]; offs[i] = v; cursor[i] = v; }
}

// ---- edge pass 2: CSR fill (src grouped by dst) -----------------------------
__global__ __launch_bounds__(256) void k_fill(const int* __restrict__ ei, int* __restrict__ cursor,
                                              int* __restrict__ csr, int E) {
  int e = blockIdx.x * 256 + threadIdx.x;
  if (e < E) {
    int src = ei[e];
    int dst = ei[E + e];
    int pos = atomicAdd(&cursor[dst], 1);
    csr[pos] = src;
  }
}

// ---- layer-1 aggregation of x (2 dims), thread per node ---------------------
__global__ __launch_bounds__(256) void k_agg1(const int* __restrict__ offs, const int* __restrict__ csr,
                                              const float* __restrict__ x, float* __restrict__ agg1, int n) {
  int node = blockIdx.x * 256 + threadIdx.x;
  if (node >= n) return;
  int beg = offs[node], end = offs[node + 1];
  float s0 = 0.f, s1 = 0.f;
  const float2* x2 = (const float2*)x;
  for (int e = beg; e < end; ++e) {
    int s = csr[e];
    float2 v = x2[s];
    s0 += v.x; s1 += v.y;
  }
  agg1[2 * node] = s0; agg1[2 * node + 1] = s1;
}

// ---- layer-1 dense: h = relu(agg1m@Wl + x@Wr + b1), bf16 out; 2 cols/thread -
__global__ __launch_bounds__(256) void k_layer1(const float* __restrict__ x, const float* __restrict__ agg1,
                                                const int* __restrict__ offs,
                                                const float* __restrict__ Wl, const float* __restrict__ Wr,
                                                const float* __restrict__ b1,
                                                unsigned int* __restrict__ h16, int n) {
  int gid = blockIdx.x * 256 + threadIdx.x;
  int node = gid >> 6;
  if (node >= n) return;
  int c = (gid & 63) * 2;
  int deg = offs[node + 1] - offs[node];
  float sc = 1.0f / (float)max(deg, 1);
  float a0 = agg1[2 * node] * sc, a1 = agg1[2 * node + 1] * sc;
  float x0 = x[2 * node], x1 = x[2 * node + 1];
  float r0 = fmaf(a0, Wl[c],     fmaf(a1, Wl[128 + c],     fmaf(x0, Wr[c],     fmaf(x1, Wr[128 + c],     b1[c]))));
  float r1 = fmaf(a0, Wl[c + 1], fmaf(a1, Wl[128 + c + 1], fmaf(x0, Wr[c + 1], fmaf(x1, Wr[128 + c + 1], b1[c + 1]))));
  r0 = r0 > 0.f ? r0 : 0.f;
  r1 = r1 > 0.f ? r1 : 0.f;
  unsigned int packed = (unsigned int)f32_to_bf16(r0) | ((unsigned int)f32_to_bf16(r1) << 16);
  h16[(size_t)node * 64 + (gid & 63)] = packed;
}

// ---- prep: Wt[col][k] bf16, k<128 from W_l2, k>=128 from W_r2 ---------------
__global__ __launch_bounds__(256) void k_prepw(const float* __restrict__ Wl2, const float* __restrict__ Wr2,
                                               unsigned short* __restrict__ wt) {
  int tid = blockIdx.x * 256 + threadIdx.x;   // tid = c*256 + k
  if (tid >= 128 * 256) return;
  int c = tid >> 8, k = tid & 255;
  float v = (k < 128) ? Wl2[k * 128 + c] : Wr2[(k - 128) * 128 + c];
  wt[tid] = f32_to_bf16(v);
}

// ---- layer-2 aggregation: wave per node, 4 edges/iter, 16B/lane gathers -----
__global__ __launch_bounds__(256) void k_agg2(const int* __restrict__ offs, const int* __restrict__ csr,
                                              const unsigned short* __restrict__ h16,
                                              unsigned int* __restrict__ a16, int n) {
  int node = blockIdx.x * 4 + (threadIdx.x >> 6);
  if (node >= n) return;
  int lane = threadIdx.x & 63;
  int g  = lane >> 4;        // edge subgroup 0..3
  int cb = lane & 15;        // col block: cols cb*8 .. cb*8+7
  int beg = offs[node], end = offs[node + 1];
  float acc[8];
#pragma unroll
  for (int j = 0; j < 8; ++j) acc[j] = 0.f;
  for (int e = beg; e < end; e += 4) {
    int idx = e + g;
    int cidx = idx < end ? idx : end - 1;     // end > beg inside loop
    float w = idx < end ? 1.f : 0.f;
    int s = csr[cidx];
    const uint4* p = (const uint4*)(h16 + (size_t)s * 128 + cb * 8);
    uint4 v = *p;
    acc[0] = fmaf(w, bf16lo(v.x), acc[0]); acc[1] = fmaf(w, bf16hi(v.x), acc[1]);
    acc[2] = fmaf(w, bf16lo(v.y), acc[2]); acc[3] = fmaf(w, bf16hi(v.y), acc[3]);
    acc[4] = fmaf(w, bf16lo(v.z), acc[4]); acc[5] = fmaf(w, bf16hi(v.z), acc[5]);
    acc[6] = fmaf(w, bf16lo(v.w), acc[6]); acc[7] = fmaf(w, bf16hi(v.w), acc[7]);
  }
#pragma unroll
  for (int j = 0; j < 8; ++j) {
    acc[j] += __shfl_xor(acc[j], 16, 64);
    acc[j] += __shfl_xor(acc[j], 32, 64);
  }
  if (g == 0) {
    int deg = end - beg;
    float scale = 1.0f / (float)max(deg, 1);
    uint4 o;
    o.x = (unsigned int)f32_to_bf16(acc[0] * scale) | ((unsigned int)f32_to_bf16(acc[1] * scale) << 16);
    o.y = (unsigned int)f32_to_bf16(acc[2] * scale) | ((unsigned int)f32_to_bf16(acc[3] * scale) << 16);
    o.z = (unsigned int)f32_to_bf16(acc[4] * scale) | ((unsigned int)f32_to_bf16(acc[5] * scale) << 16);
    o.w = (unsigned int)f32_to_bf16(acc[6] * scale) | ((unsigned int)f32_to_bf16(acc[7] * scale) << 16);
    // a16 row = 128 bf16 = 64 uints  (R1 fix: was node*32 -> overlapped rows)
    *(uint4*)(a16 + (size_t)node * 64 + cb * 4) = o;
  }
}

// ---- layer-2 GEMM: out[N,128] = [agg2|h](bf16) @ Wt(bf16) + b2, MFMA --------
// wave handles 16 rows x 128 cols, K=256 (8 chunks of 32); 64 MFMAs/wave.
__global__ __launch_bounds__(256) void k_gemm(const unsigned short* __restrict__ a16,
                                              const unsigned short* __restrict__ h16,
                                              const unsigned short* __restrict__ wt,
                                              const float* __restrict__ b2,
                                              float* __restrict__ out, int nrows) {
  int wave = blockIdx.x * 4 + (threadIdx.x >> 6);
  int lane = threadIdx.x & 63;
  int m16 = lane & 15, quad = lane >> 4;
  int r0 = wave * 16;
  if (r0 >= nrows) return;
  int r = r0 + m16;
  int rc = r < nrows ? r : nrows - 1;

  f32x4 acc[8];
#pragma unroll
  for (int t = 0; t < 8; ++t) acc[t] = (f32x4){0.f, 0.f, 0.f, 0.f};

#pragma unroll
  for (int ch = 0; ch < 8; ++ch) {
    const unsigned short* abase = (ch < 4) ? a16 : h16;
    const unsigned short* ap = abase + (size_t)rc * 128 + (ch & 3) * 32 + quad * 8;
    s16x8 afrag = *(const s16x8*)ap;   // A[m=lane&15][k=quad*8+j]
#pragma unroll
    for (int t = 0; t < 8; ++t) {
      const unsigned short* bp = wt + (size_t)(t * 16 + m16) * 256 + ch * 32 + quad * 8;
      s16x8 bfrag = *(const s16x8*)bp; // B[k=quad*8+j][n=lane&15]
      acc[t] = __builtin_amdgcn_mfma_f32_16x16x32_bf16(afrag, bfrag, acc[t], 0, 0, 0);
    }
  }

#pragma unroll
  for (int t = 0; t < 8; ++t) {
    int col = t * 16 + m16;
    float bias = b2[col];
#pragma unroll
    for (int i = 0; i < 4; ++i) {
      int row = r0 + quad * 4 + i;   // C/D: col=lane&15, row=quad*4+reg
      if (row < nrows) out[(size_t)row * 128 + col] = acc[t][i] + bias;
    }
  }
}

// ---------------------------------------------------------------------------
extern "C" void kernel_launch(void* const* d_in, const int* in_sizes, int n_in,
                              void* d_out, int out_size, void* d_ws, size_t ws_size,
                              hipStream_t stream) {
  const float* x    = (const float*)d_in[0];
  const int*   ei   = (const int*)d_in[1];
  const float* Wl1  = (const float*)d_in[2];
  const float* Wr1  = (const float*)d_in[3];
  const float* b1   = (const float*)d_in[4];
  const float* Wl2  = (const float*)d_in[5];
  const float* Wr2  = (const float*)d_in[6];
  const float* b2   = (const float*)d_in[7];
  float* out = (float*)d_out;

  const int N = in_sizes[0] / 2;     // 100000
  const int E = in_sizes[1] / 2;     // 1600000

  // workspace carve-up (256B aligned)
  char* p = (char*)d_ws;
  auto take = [&](size_t bytes) { char* r = p; p += (bytes + 255) & ~(size_t)255; return r; };
  int* degi            = (int*)take((size_t)N * 4);
  int* offs            = (int*)take((size_t)(N + 1) * 4);
  int* cursor          = (int*)take((size_t)N * 4);
  int* btot            = (int*)take(128 * 4);
  int* bpre            = (int*)take(128 * 4);
  int* csr             = (int*)take((size_t)E * 4);
  float* agg1          = (float*)take((size_t)N * 2 * 4);
  unsigned short* h16  = (unsigned short*)take((size_t)N * 128 * 2);
  unsigned short* a16  = (unsigned short*)take((size_t)N * 128 * 2);
  unsigned short* wt   = (unsigned short*)take((size_t)128 * 256 * 2);

  const int nb1 = (N + 1023) / 1024;           // 98 scan blocks

  hipMemsetAsync(degi, 0, (size_t)N * 4, stream);

  k_count <<<(E + 255) / 256, 256, 0, stream>>>(ei, degi, E);
  k_scan1 <<<nb1, 256, 0, stream>>>(degi, offs, btot, N);
  k_scan2 <<<1, 128, 0, stream>>>(btot, bpre, nb1);
  k_scan3 <<<(N + 255) / 256, 256, 0, stream>>>(offs, cursor, bpre, N, E);
  k_fill  <<<(E + 255) / 256, 256, 0, stream>>>(ei, cursor, csr, E);
  k_agg1  <<<(N + 255) / 256, 256, 0, stream>>>(offs, csr, x, agg1, N);
  k_layer1<<<((size_t)N * 64 + 255) / 256, 256, 0, stream>>>(x, agg1, offs, Wl1, Wr1, b1,
                                                             (unsigned int*)h16, N);
  k_prepw <<<(128 * 256) / 256, 256, 0, stream>>>(Wl2, Wr2, wt);
  k_agg2  <<<(N + 3) / 4, 256, 0, stream>>>(offs, csr, h16, (unsigned int*)a16, N);
  k_gemm  <<<((N + 15) / 16 + 3) / 4, 256, 0, stream>>>(a16, h16, wt, b2, out, N);
}

// Round 3
// 315.916 us; speedup vs baseline: 1.4370x; 1.4370x over previous
//
#include <hip/hip_runtime.h>

// ---------------------------------------------------------------------------
// GraphSAGE 2-layer, mean aggregation.
//   L1: h = relu( mean_nbr(x) @ W_l1 + x @ W_r1 + b1 )   (IN=2 -> aggregate x first)
//   L2: out = mean_nbr(h) @ W_l2 + h @ W_r2 + b2
// R2: CSR build via 2-level MSD binning (bucket = dst>>7, 128 nodes/bucket).
//     Replaces k_count + node-scan + k_fill (k_fill had 17x write amp: random
//     4B scatter over 6.4MB -> 108MB WRITE_SIZE). All scatter now lands in
//     bucket-local windows owned by one CU.
// ---------------------------------------------------------------------------

using f32x4 = __attribute__((ext_vector_type(4))) float;
using s16x8 = __attribute__((ext_vector_type(8))) short;

__device__ __forceinline__ unsigned short f32_to_bf16(float f) {
  unsigned int u = __float_as_uint(f);
  u += 0x7fffu + ((u >> 16) & 1u);          // round-to-nearest-even
  return (unsigned short)(u >> 16);
}
__device__ __forceinline__ float bf16lo(unsigned int p) { return __uint_as_float(p << 16); }
__device__ __forceinline__ float bf16hi(unsigned int p) { return __uint_as_float(p & 0xffff0000u); }

#define EDGE_TILE 4096

// ---- bin pass 1: bucket histogram (LDS-local, one global atomic/bucket) ----
__global__ __launch_bounds__(256) void k_bhist(const int* __restrict__ ei, int* __restrict__ bcnt,
                                               int E, int nb) {
  __shared__ int h[1024];
  int t = threadIdx.x;
  for (int i = t; i < nb; i += 256) h[i] = 0;
  __syncthreads();
  int tbeg = blockIdx.x * EDGE_TILE;
  int tend = min(tbeg + EDGE_TILE, E);
  const int* dstp = ei + E;
  for (int i = tbeg + t; i < tend; i += 256) atomicAdd(&h[dstp[i] >> 7], 1);
  __syncthreads();
  for (int i = t; i < nb; i += 256) if (h[i]) atomicAdd(&bcnt[i], h[i]);
}

// ---- bin pass 2: scan bucket counts -> bases + cursor copy ------------------
__global__ __launch_bounds__(1024) void k_bscan(const int* __restrict__ bcnt, int* __restrict__ bbase,
                                                int* __restrict__ bcur, int nb, int E) {
  __shared__ int sm[2][1024];
  int t = threadIdx.x;
  int v0 = (t < nb) ? bcnt[t] : 0;
  sm[0][t] = v0;
  __syncthreads();
  int src = 0;
  for (int st = 1; st < 1024; st <<= 1) {
    int v = sm[src][t];
    if (t >= st) v += sm[src][t - st];
    sm[src ^ 1][t] = v; __syncthreads(); src ^= 1;
  }
  int ex = sm[src][t] - v0;
  if (t < nb) { bbase[t] = ex; bcur[t] = ex; }
  if (t == 0) bbase[nb] = E;
}

// ---- bin pass 3: scatter (src,dst) into bucket-grouped ebuf -----------------
__global__ __launch_bounds__(256) void k_bscatter(const int* __restrict__ ei, int* __restrict__ bcur,
                                                  uint2* __restrict__ ebuf, int E, int nb) {
  __shared__ int h[1024];
  __shared__ int base[1024];
  int t = threadIdx.x;
  for (int i = t; i < nb; i += 256) h[i] = 0;
  __syncthreads();
  int tbeg = blockIdx.x * EDGE_TILE;
  int tend = min(tbeg + EDGE_TILE, E);
  const int* srcp = ei;
  const int* dstp = ei + E;
  for (int i = tbeg + t; i < tend; i += 256) atomicAdd(&h[dstp[i] >> 7], 1);
  __syncthreads();
  for (int i = t; i < nb; i += 256) {
    int c = h[i];
    base[i] = c ? atomicAdd(&bcur[i], c) : 0;
    h[i] = 0;                                   // reuse as rank cursor
  }
  __syncthreads();
  for (int i = tbeg + t; i < tend; i += 256) {
    int d = dstp[i];
    int b = d >> 7;
    int r = atomicAdd(&h[b], 1);
    ebuf[base[b] + r] = make_uint2((unsigned)srcp[i], (unsigned)d);
  }
}

// ---- bin pass 4: per-bucket local CSR build (offs + csr), block per bucket --
__global__ __launch_bounds__(256) void k_bucket_csr(const uint2* __restrict__ ebuf,
                                                    const int* __restrict__ bbase,
                                                    int* __restrict__ offs, int* __restrict__ csr,
                                                    int N, int nb) {
  __shared__ int deg[128];
  __shared__ int loff[128];
  __shared__ int cur[128];
  int b = blockIdx.x;
  int t = threadIdx.x;
  int lo = bbase[b], hi = bbase[b + 1];
  if (t < 128) deg[t] = 0;
  __syncthreads();
  for (int i = lo + t; i < hi; i += 256) atomicAdd(&deg[ebuf[i].y & 127], 1);
  __syncthreads();
  if (t < 128) loff[t] = deg[t];
  __syncthreads();
  for (int st = 1; st < 128; st <<= 1) {
    int v = 0;
    if (t < 128 && t >= st) v = loff[t - st];
    __syncthreads();
    if (t < 128) loff[t] += v;
    __syncthreads();
  }
  if (t < 128) {
    int ex = loff[t] - deg[t];                 // exclusive prefix
    cur[t] = ex;
    int node = b * 128 + t;
    if (node < N) offs[node] = lo + ex;
  }
  if (b == nb - 1 && t == 0) offs[N] = hi;
  __syncthreads();
  for (int i = lo + t; i < hi; i += 256) {
    uint2 e = ebuf[i];
    int r = atomicAdd(&cur[e.y & 127], 1);
    csr[lo + r] = (int)e.x;
  }
}

// ---- layer-1 aggregation of x (2 dims), thread per node ---------------------
__global__ __launch_bounds__(256) void k_agg1(const int* __restrict__ offs, const int* __restrict__ csr,
                                              const float* __restrict__ x, float* __restrict__ agg1, int n) {
  int node = blockIdx.x * 256 + threadIdx.x;
  if (node >= n) return;
  int beg = offs[node], end = offs[node + 1];
  float s0 = 0.f, s1 = 0.f;
  const float2* x2 = (const float2*)x;
  for (int e = beg; e < end; ++e) {
    int s = csr[e];
    float2 v = x2[s];
    s0 += v.x; s1 += v.y;
  }
  agg1[2 * node] = s0; agg1[2 * node + 1] = s1;
}

// ---- layer-1 dense: h = relu(agg1m@Wl + x@Wr + b1), bf16 out; 2 cols/thread -
__global__ __launch_bounds__(256) void k_layer1(const float* __restrict__ x, const float* __restrict__ agg1,
                                                const int* __restrict__ offs,
                                                const float* __restrict__ Wl, const float* __restrict__ Wr,
                                                const float* __restrict__ b1,
                                                unsigned int* __restrict__ h16, int n) {
  int gid = blockIdx.x * 256 + threadIdx.x;
  int node = gid >> 6;
  if (node >= n) return;
  int c = (gid & 63) * 2;
  int deg = offs[node + 1] - offs[node];
  float sc = 1.0f / (float)max(deg, 1);
  float a0 = agg1[2 * node] * sc, a1 = agg1[2 * node + 1] * sc;
  float x0 = x[2 * node], x1 = x[2 * node + 1];
  float r0 = fmaf(a0, Wl[c],     fmaf(a1, Wl[128 + c],     fmaf(x0, Wr[c],     fmaf(x1, Wr[128 + c],     b1[c]))));
  float r1 = fmaf(a0, Wl[c + 1], fmaf(a1, Wl[128 + c + 1], fmaf(x0, Wr[c + 1], fmaf(x1, Wr[128 + c + 1], b1[c + 1]))));
  r0 = r0 > 0.f ? r0 : 0.f;
  r1 = r1 > 0.f ? r1 : 0.f;
  unsigned int packed = (unsigned int)f32_to_bf16(r0) | ((unsigned int)f32_to_bf16(r1) << 16);
  h16[(size_t)node * 64 + (gid & 63)] = packed;
}

// ---- prep: Wt[col][k] bf16, k<128 from W_l2, k>=128 from W_r2 ---------------
__global__ __launch_bounds__(256) void k_prepw(const float* __restrict__ Wl2, const float* __restrict__ Wr2,
                                               unsigned short* __restrict__ wt) {
  int tid = blockIdx.x * 256 + threadIdx.x;   // tid = c*256 + k
  if (tid >= 128 * 256) return;
  int c = tid >> 8, k = tid & 255;
  float v = (k < 128) ? Wl2[k * 128 + c] : Wr2[(k - 128) * 128 + c];
  wt[tid] = f32_to_bf16(v);
}

// ---- layer-2 aggregation: wave per node, 4 edges/iter, 16B/lane gathers -----
__global__ __launch_bounds__(256) void k_agg2(const int* __restrict__ offs, const int* __restrict__ csr,
                                              const unsigned short* __restrict__ h16,
                                              unsigned int* __restrict__ a16, int n) {
  int node = blockIdx.x * 4 + (threadIdx.x >> 6);
  if (node >= n) return;
  int lane = threadIdx.x & 63;
  int g  = lane >> 4;        // edge subgroup 0..3
  int cb = lane & 15;        // col block: cols cb*8 .. cb*8+7
  int beg = offs[node], end = offs[node + 1];
  float acc[8];
#pragma unroll
  for (int j = 0; j < 8; ++j) acc[j] = 0.f;
  for (int e = beg; e < end; e += 4) {
    int idx = e + g;
    int cidx = idx < end ? idx : end - 1;     // end > beg inside loop
    float w = idx < end ? 1.f : 0.f;
    int s = csr[cidx];
    const uint4* p = (const uint4*)(h16 + (size_t)s * 128 + cb * 8);
    uint4 v = *p;
    acc[0] = fmaf(w, bf16lo(v.x), acc[0]); acc[1] = fmaf(w, bf16hi(v.x), acc[1]);
    acc[2] = fmaf(w, bf16lo(v.y), acc[2]); acc[3] = fmaf(w, bf16hi(v.y), acc[3]);
    acc[4] = fmaf(w, bf16lo(v.z), acc[4]); acc[5] = fmaf(w, bf16hi(v.z), acc[5]);
    acc[6] = fmaf(w, bf16lo(v.w), acc[6]); acc[7] = fmaf(w, bf16hi(v.w), acc[7]);
  }
#pragma unroll
  for (int j = 0; j < 8; ++j) {
    acc[j] += __shfl_xor(acc[j], 16, 64);
    acc[j] += __shfl_xor(acc[j], 32, 64);
  }
  if (g == 0) {
    int deg = end - beg;
    float scale = 1.0f / (float)max(deg, 1);
    uint4 o;
    o.x = (unsigned int)f32_to_bf16(acc[0] * scale) | ((unsigned int)f32_to_bf16(acc[1] * scale) << 16);
    o.y = (unsigned int)f32_to_bf16(acc[2] * scale) | ((unsigned int)f32_to_bf16(acc[3] * scale) << 16);
    o.z = (unsigned int)f32_to_bf16(acc[4] * scale) | ((unsigned int)f32_to_bf16(acc[5] * scale) << 16);
    o.w = (unsigned int)f32_to_bf16(acc[6] * scale) | ((unsigned int)f32_to_bf16(acc[7] * scale) << 16);
    *(uint4*)(a16 + (size_t)node * 64 + cb * 4) = o;   // row = 64 uints
  }
}

// ---- layer-2 GEMM: out[N,128] = [agg2|h](bf16) @ Wt(bf16) + b2, MFMA --------
__global__ __launch_bounds__(256) void k_gemm(const unsigned short* __restrict__ a16,
                                              const unsigned short* __restrict__ h16,
                                              const unsigned short* __restrict__ wt,
                                              const float* __restrict__ b2,
                                              float* __restrict__ out, int nrows) {
  int wave = blockIdx.x * 4 + (threadIdx.x >> 6);
  int lane = threadIdx.x & 63;
  int m16 = lane & 15, quad = lane >> 4;
  int r0 = wave * 16;
  if (r0 >= nrows) return;
  int r = r0 + m16;
  int rc = r < nrows ? r : nrows - 1;

  f32x4 acc[8];
#pragma unroll
  for (int t = 0; t < 8; ++t) acc[t] = (f32x4){0.f, 0.f, 0.f, 0.f};

#pragma unroll
  for (int ch = 0; ch < 8; ++ch) {
    const unsigned short* abase = (ch < 4) ? a16 : h16;
    const unsigned short* ap = abase + (size_t)rc * 128 + (ch & 3) * 32 + quad * 8;
    s16x8 afrag = *(const s16x8*)ap;   // A[m=lane&15][k=quad*8+j]
#pragma unroll
    for (int t = 0; t < 8; ++t) {
      const unsigned short* bp = wt + (size_t)(t * 16 + m16) * 256 + ch * 32 + quad * 8;
      s16x8 bfrag = *(const s16x8*)bp; // B[k=quad*8+j][n=lane&15]
      acc[t] = __builtin_amdgcn_mfma_f32_16x16x32_bf16(afrag, bfrag, acc[t], 0, 0, 0);
    }
  }

#pragma unroll
  for (int t = 0; t < 8; ++t) {
    int col = t * 16 + m16;
    float bias = b2[col];
#pragma unroll
    for (int i = 0; i < 4; ++i) {
      int row = r0 + quad * 4 + i;   // C/D: col=lane&15, row=quad*4+reg
      if (row < nrows) out[(size_t)row * 128 + col] = acc[t][i] + bias;
    }
  }
}

// ---------------------------------------------------------------------------
extern "C" void kernel_launch(void* const* d_in, const int* in_sizes, int n_in,
                              void* d_out, int out_size, void* d_ws, size_t ws_size,
                              hipStream_t stream) {
  const float* x    = (const float*)d_in[0];
  const int*   ei   = (const int*)d_in[1];
  const float* Wl1  = (const float*)d_in[2];
  const float* Wr1  = (const float*)d_in[3];
  const float* b1   = (const float*)d_in[4];
  const float* Wl2  = (const float*)d_in[5];
  const float* Wr2  = (const float*)d_in[6];
  const float* b2   = (const float*)d_in[7];
  float* out = (float*)d_out;

  const int N = in_sizes[0] / 2;     // 100000
  const int E = in_sizes[1] / 2;     // 1600000
  const int nb = (N + 127) >> 7;     // 782 buckets

  // workspace carve-up (256B aligned)
  char* p = (char*)d_ws;
  auto take = [&](size_t bytes) { char* r = p; p += (bytes + 255) & ~(size_t)255; return r; };
  int* bcnt            = (int*)take(1024 * 4);
  int* bbase           = (int*)take(1025 * 4);
  int* bcur            = (int*)take(1024 * 4);
  int* offs            = (int*)take((size_t)(N + 1) * 4);
  int* csr             = (int*)take((size_t)E * 4);
  uint2* ebuf          = (uint2*)take((size_t)E * 8);
  float* agg1          = (float*)take((size_t)N * 2 * 4);
  unsigned short* h16  = (unsigned short*)take((size_t)N * 128 * 2);
  unsigned short* a16  = (unsigned short*)take((size_t)N * 128 * 2);
  unsigned short* wt   = (unsigned short*)take((size_t)128 * 256 * 2);

  const int nblk_e = (E + EDGE_TILE - 1) / EDGE_TILE;   // 391

  hipMemsetAsync(bcnt, 0, 1024 * 4, stream);

  k_bhist     <<<nblk_e, 256, 0, stream>>>(ei, bcnt, E, nb);
  k_bscan     <<<1, 1024, 0, stream>>>(bcnt, bbase, bcur, nb, E);
  k_bscatter  <<<nblk_e, 256, 0, stream>>>(ei, bcur, ebuf, E, nb);
  k_bucket_csr<<<nb, 256, 0, stream>>>(ebuf, bbase, offs, csr, N, nb);
  k_agg1      <<<(N + 255) / 256, 256, 0, stream>>>(offs, csr, x, agg1, N);
  k_layer1    <<<((size_t)N * 64 + 255) / 256, 256, 0, stream>>>(x, agg1, offs, Wl1, Wr1, b1,
                                                                 (unsigned int*)h16, N);
  k_prepw     <<<(128 * 256) / 256, 256, 0, stream>>>(Wl2, Wr2, wt);
  k_agg2      <<<(N + 3) / 4, 256, 0, stream>>>(offs, csr, h16, (unsigned int*)a16, N);
  k_gemm      <<<((N + 15) / 16 + 3) / 4, 256, 0, stream>>>(a16, h16, wt, b2, out, N);
}

// Round 4
// 277.501 us; speedup vs baseline: 1.6359x; 1.1384x over previous
//
#include <hip/hip_runtime.h>

// ---------------------------------------------------------------------------
// GraphSAGE 2-layer, mean aggregation.
//   L1: h = relu( mean_nbr(x) @ W_l1 + x @ W_r1 + b1 )   (IN=2 -> aggregate x first)
//   L2: out = mean_nbr(h) @ W_l2 + h @ W_r2 + b2
// R2: CSR via 2-level MSD binning (bucket = dst>>7).
// R3: k_gemm was latency-bound (MfmaUtil 3.4%, VALU 4%, 14% HBM): 64 serialized
//     L2-latency B-fragment loads/wave @ 52 VGPRs. Now: B staged in LDS per
//     block (col-half, 64x264 shorts, +8 pad -> min-bank b128 reads), 4 waves
//     x 16-row tiles, A loads from global, 32 ds_read_b128 + 32 MFMA per tile.
// ---------------------------------------------------------------------------

using f32x4 = __attribute__((ext_vector_type(4))) float;
using s16x8 = __attribute__((ext_vector_type(8))) short;

__device__ __forceinline__ unsigned short f32_to_bf16(float f) {
  unsigned int u = __float_as_uint(f);
  u += 0x7fffu + ((u >> 16) & 1u);          // round-to-nearest-even
  return (unsigned short)(u >> 16);
}
__device__ __forceinline__ float bf16lo(unsigned int p) { return __uint_as_float(p << 16); }
__device__ __forceinline__ float bf16hi(unsigned int p) { return __uint_as_float(p & 0xffff0000u); }

#define EDGE_TILE 4096

// ---- bin pass 1: bucket histogram (LDS-local, one global atomic/bucket) ----
__global__ __launch_bounds__(256) void k_bhist(const int* __restrict__ ei, int* __restrict__ bcnt,
                                               int E, int nb) {
  __shared__ int h[1024];
  int t = threadIdx.x;
  for (int i = t; i < nb; i += 256) h[i] = 0;
  __syncthreads();
  int tbeg = blockIdx.x * EDGE_TILE;
  int tend = min(tbeg + EDGE_TILE, E);
  const int* dstp = ei + E;
  for (int i = tbeg + t; i < tend; i += 256) atomicAdd(&h[dstp[i] >> 7], 1);
  __syncthreads();
  for (int i = t; i < nb; i += 256) if (h[i]) atomicAdd(&bcnt[i], h[i]);
}

// ---- bin pass 2: scan bucket counts -> bases + cursor copy ------------------
__global__ __launch_bounds__(1024) void k_bscan(const int* __restrict__ bcnt, int* __restrict__ bbase,
                                                int* __restrict__ bcur, int nb, int E) {
  __shared__ int sm[2][1024];
  int t = threadIdx.x;
  int v0 = (t < nb) ? bcnt[t] : 0;
  sm[0][t] = v0;
  __syncthreads();
  int src = 0;
  for (int st = 1; st < 1024; st <<= 1) {
    int v = sm[src][t];
    if (t >= st) v += sm[src][t - st];
    sm[src ^ 1][t] = v; __syncthreads(); src ^= 1;
  }
  int ex = sm[src][t] - v0;
  if (t < nb) { bbase[t] = ex; bcur[t] = ex; }
  if (t == 0) bbase[nb] = E;
}

// ---- bin pass 3: scatter (src,dst) into bucket-grouped ebuf -----------------
__global__ __launch_bounds__(256) void k_bscatter(const int* __restrict__ ei, int* __restrict__ bcur,
                                                  uint2* __restrict__ ebuf, int E, int nb) {
  __shared__ int h[1024];
  __shared__ int base[1024];
  int t = threadIdx.x;
  for (int i = t; i < nb; i += 256) h[i] = 0;
  __syncthreads();
  int tbeg = blockIdx.x * EDGE_TILE;
  int tend = min(tbeg + EDGE_TILE, E);
  const int* srcp = ei;
  const int* dstp = ei + E;
  for (int i = tbeg + t; i < tend; i += 256) atomicAdd(&h[dstp[i] >> 7], 1);
  __syncthreads();
  for (int i = t; i < nb; i += 256) {
    int c = h[i];
    base[i] = c ? atomicAdd(&bcur[i], c) : 0;
    h[i] = 0;                                   // reuse as rank cursor
  }
  __syncthreads();
  for (int i = tbeg + t; i < tend; i += 256) {
    int d = dstp[i];
    int b = d >> 7;
    int r = atomicAdd(&h[b], 1);
    ebuf[base[b] + r] = make_uint2((unsigned)srcp[i], (unsigned)d);
  }
}

// ---- bin pass 4: per-bucket local CSR build (offs + csr), block per bucket --
__global__ __launch_bounds__(256) void k_bucket_csr(const uint2* __restrict__ ebuf,
                                                    const int* __restrict__ bbase,
                                                    int* __restrict__ offs, int* __restrict__ csr,
                                                    int N, int nb) {
  __shared__ int deg[128];
  __shared__ int loff[128];
  __shared__ int cur[128];
  int b = blockIdx.x;
  int t = threadIdx.x;
  int lo = bbase[b], hi = bbase[b + 1];
  if (t < 128) deg[t] = 0;
  __syncthreads();
  for (int i = lo + t; i < hi; i += 256) atomicAdd(&deg[ebuf[i].y & 127], 1);
  __syncthreads();
  if (t < 128) loff[t] = deg[t];
  __syncthreads();
  for (int st = 1; st < 128; st <<= 1) {
    int v = 0;
    if (t < 128 && t >= st) v = loff[t - st];
    __syncthreads();
    if (t < 128) loff[t] += v;
    __syncthreads();
  }
  if (t < 128) {
    int ex = loff[t] - deg[t];                 // exclusive prefix
    cur[t] = ex;
    int node = b * 128 + t;
    if (node < N) offs[node] = lo + ex;
  }
  if (b == nb - 1 && t == 0) offs[N] = hi;
  __syncthreads();
  for (int i = lo + t; i < hi; i += 256) {
    uint2 e = ebuf[i];
    int r = atomicAdd(&cur[e.y & 127], 1);
    csr[lo + r] = (int)e.x;
  }
}

// ---- layer-1 aggregation of x (2 dims), thread per node ---------------------
__global__ __launch_bounds__(256) void k_agg1(const int* __restrict__ offs, const int* __restrict__ csr,
                                              const float* __restrict__ x, float* __restrict__ agg1, int n) {
  int node = blockIdx.x * 256 + threadIdx.x;
  if (node >= n) return;
  int beg = offs[node], end = offs[node + 1];
  float s0 = 0.f, s1 = 0.f;
  const float2* x2 = (const float2*)x;
  for (int e = beg; e < end; ++e) {
    int s = csr[e];
    float2 v = x2[s];
    s0 += v.x; s1 += v.y;
  }
  agg1[2 * node] = s0; agg1[2 * node + 1] = s1;
}

// ---- layer-1 dense: h = relu(agg1m@Wl + x@Wr + b1), bf16 out; 2 cols/thread -
__global__ __launch_bounds__(256) void k_layer1(const float* __restrict__ x, const float* __restrict__ agg1,
                                                const int* __restrict__ offs,
                                                const float* __restrict__ Wl, const float* __restrict__ Wr,
                                                const float* __restrict__ b1,
                                                unsigned int* __restrict__ h16, int n) {
  int gid = blockIdx.x * 256 + threadIdx.x;
  int node = gid >> 6;
  if (node >= n) return;
  int c = (gid & 63) * 2;
  int deg = offs[node + 1] - offs[node];
  float sc = 1.0f / (float)max(deg, 1);
  float a0 = agg1[2 * node] * sc, a1 = agg1[2 * node + 1] * sc;
  float x0 = x[2 * node], x1 = x[2 * node + 1];
  float r0 = fmaf(a0, Wl[c],     fmaf(a1, Wl[128 + c],     fmaf(x0, Wr[c],     fmaf(x1, Wr[128 + c],     b1[c]))));
  float r1 = fmaf(a0, Wl[c + 1], fmaf(a1, Wl[128 + c + 1], fmaf(x0, Wr[c + 1], fmaf(x1, Wr[128 + c + 1], b1[c + 1]))));
  r0 = r0 > 0.f ? r0 : 0.f;
  r1 = r1 > 0.f ? r1 : 0.f;
  unsigned int packed = (unsigned int)f32_to_bf16(r0) | ((unsigned int)f32_to_bf16(r1) << 16);
  h16[(size_t)node * 64 + (gid & 63)] = packed;
}

// ---- prep: Wt[col][k] bf16, k<128 from W_l2, k>=128 from W_r2 ---------------
__global__ __launch_bounds__(256) void k_prepw(const float* __restrict__ Wl2, const float* __restrict__ Wr2,
                                               unsigned short* __restrict__ wt) {
  int tid = blockIdx.x * 256 + threadIdx.x;   // tid = c*256 + k
  if (tid >= 128 * 256) return;
  int c = tid >> 8, k = tid & 255;
  float v = (k < 128) ? Wl2[k * 128 + c] : Wr2[(k - 128) * 128 + c];
  wt[tid] = f32_to_bf16(v);
}

// ---- layer-2 aggregation: wave per node, 4 edges/iter, 16B/lane gathers -----
__global__ __launch_bounds__(256) void k_agg2(const int* __restrict__ offs, const int* __restrict__ csr,
                                              const unsigned short* __restrict__ h16,
                                              unsigned int* __restrict__ a16, int n) {
  int node = blockIdx.x * 4 + (threadIdx.x >> 6);
  if (node >= n) return;
  int lane = threadIdx.x & 63;
  int g  = lane >> 4;        // edge subgroup 0..3
  int cb = lane & 15;        // col block: cols cb*8 .. cb*8+7
  int beg = offs[node], end = offs[node + 1];
  float acc[8];
#pragma unroll
  for (int j = 0; j < 8; ++j) acc[j] = 0.f;
  for (int e = beg; e < end; e += 4) {
    int idx = e + g;
    int cidx = idx < end ? idx : end - 1;     // end > beg inside loop
    float w = idx < end ? 1.f : 0.f;
    int s = csr[cidx];
    const uint4* p = (const uint4*)(h16 + (size_t)s * 128 + cb * 8);
    uint4 v = *p;
    acc[0] = fmaf(w, bf16lo(v.x), acc[0]); acc[1] = fmaf(w, bf16hi(v.x), acc[1]);
    acc[2] = fmaf(w, bf16lo(v.y), acc[2]); acc[3] = fmaf(w, bf16hi(v.y), acc[3]);
    acc[4] = fmaf(w, bf16lo(v.z), acc[4]); acc[5] = fmaf(w, bf16hi(v.z), acc[5]);
    acc[6] = fmaf(w, bf16lo(v.w), acc[6]); acc[7] = fmaf(w, bf16hi(v.w), acc[7]);
  }
#pragma unroll
  for (int j = 0; j < 8; ++j) {
    acc[j] += __shfl_xor(acc[j], 16, 64);
    acc[j] += __shfl_xor(acc[j], 32, 64);
  }
  if (g == 0) {
    int deg = end - beg;
    float scale = 1.0f / (float)max(deg, 1);
    uint4 o;
    o.x = (unsigned int)f32_to_bf16(acc[0] * scale) | ((unsigned int)f32_to_bf16(acc[1] * scale) << 16);
    o.y = (unsigned int)f32_to_bf16(acc[2] * scale) | ((unsigned int)f32_to_bf16(acc[3] * scale) << 16);
    o.z = (unsigned int)f32_to_bf16(acc[4] * scale) | ((unsigned int)f32_to_bf16(acc[5] * scale) << 16);
    o.w = (unsigned int)f32_to_bf16(acc[6] * scale) | ((unsigned int)f32_to_bf16(acc[7] * scale) << 16);
    *(uint4*)(a16 + (size_t)node * 64 + cb * 4) = o;   // row = 64 uints
  }
}

// ---- layer-2 GEMM: out[N,128] = [agg2|h](bf16) @ Wt(bf16) + b2, MFMA --------
// Block: one column-half (64 cols) staged in LDS (row stride 264 shorts, +16B
// pad -> minimum-bank b128 reads); 4 waves x one 16-row tile each.
__global__ __launch_bounds__(256) void k_gemm(const unsigned short* __restrict__ a16,
                                              const unsigned short* __restrict__ h16,
                                              const unsigned short* __restrict__ wt,
                                              const float* __restrict__ b2,
                                              float* __restrict__ out, int nrows) {
  __shared__ unsigned short bs[64 * 264];   // 33792 B
  int half = blockIdx.x & 1;
  int tg   = blockIdx.x >> 1;

  // stage wt col-half into LDS: 64 rows x 512 B, coalesced 16B chunks
#pragma unroll
  for (int i = 0; i < 8; ++i) {
    int c = threadIdx.x + i * 256;          // 0..2047
    int row = c >> 5, off = c & 31;         // off in 16B units
    *(uint4*)(bs + row * 264 + off * 8) =
        *(const uint4*)(wt + ((size_t)(half * 64 + row)) * 256 + off * 8);
  }
  __syncthreads();

  int wv   = threadIdx.x >> 6;
  int lane = threadIdx.x & 63;
  int m16 = lane & 15, quad = lane >> 4;
  int tile = tg * 4 + wv;
  if (tile * 16 >= nrows) return;

  int r  = tile * 16 + m16;
  int rc = r < nrows ? r : nrows - 1;
  const unsigned short* arow = a16 + (size_t)rc * 128 + quad * 8;
  const unsigned short* hrow = h16 + (size_t)rc * 128 + quad * 8;

  s16x8 afrag[8];
#pragma unroll
  for (int c4 = 0; c4 < 4; ++c4) {
    afrag[c4]     = *(const s16x8*)(arow + c4 * 32);   // A[m][k], k-chunk c4
    afrag[4 + c4] = *(const s16x8*)(hrow + c4 * 32);
  }

  f32x4 acc[4];
#pragma unroll
  for (int t = 0; t < 4; ++t) acc[t] = (f32x4){0.f, 0.f, 0.f, 0.f};

  const unsigned short* bbase = bs + m16 * 264 + quad * 8;
#pragma unroll
  for (int ch = 0; ch < 8; ++ch) {
#pragma unroll
    for (int t = 0; t < 4; ++t) {
      s16x8 bf = *(const s16x8*)(bbase + t * 16 * 264 + ch * 32); // B[k][n]
      acc[t] = __builtin_amdgcn_mfma_f32_16x16x32_bf16(afrag[ch], bf, acc[t], 0, 0, 0);
    }
  }

#pragma unroll
  for (int t = 0; t < 4; ++t) {
    int col = half * 64 + t * 16 + m16;
    float bias = b2[col];
#pragma unroll
    for (int i = 0; i < 4; ++i) {
      int row = tile * 16 + quad * 4 + i;   // C/D: col=lane&15, row=quad*4+reg
      if (row < nrows) out[(size_t)row * 128 + col] = acc[t][i] + bias;
    }
  }
}

// ---------------------------------------------------------------------------
extern "C" void kernel_launch(void* const* d_in, const int* in_sizes, int n_in,
                              void* d_out, int out_size, void* d_ws, size_t ws_size,
                              hipStream_t stream) {
  const float* x    = (const float*)d_in[0];
  const int*   ei   = (const int*)d_in[1];
  const float* Wl1  = (const float*)d_in[2];
  const float* Wr1  = (const float*)d_in[3];
  const float* b1   = (const float*)d_in[4];
  const float* Wl2  = (const float*)d_in[5];
  const float* Wr2  = (const float*)d_in[6];
  const float* b2   = (const float*)d_in[7];
  float* out = (float*)d_out;

  const int N = in_sizes[0] / 2;     // 100000
  const int E = in_sizes[1] / 2;     // 1600000
  const int nb = (N + 127) >> 7;     // 782 buckets

  // workspace carve-up (256B aligned)
  char* p = (char*)d_ws;
  auto take = [&](size_t bytes) { char* r = p; p += (bytes + 255) & ~(size_t)255; return r; };
  int* bcnt            = (int*)take(1024 * 4);
  int* bbase           = (int*)take(1025 * 4);
  int* bcur            = (int*)take(1024 * 4);
  int* offs            = (int*)take((size_t)(N + 1) * 4);
  int* csr             = (int*)take((size_t)E * 4);
  uint2* ebuf          = (uint2*)take((size_t)E * 8);
  float* agg1          = (float*)take((size_t)N * 2 * 4);
  unsigned short* h16  = (unsigned short*)take((size_t)N * 128 * 2);
  unsigned short* a16  = (unsigned short*)take((size_t)N * 128 * 2);
  unsigned short* wt   = (unsigned short*)take((size_t)128 * 256 * 2);

  const int nblk_e = (E + EDGE_TILE - 1) / EDGE_TILE;   // 391
  const int ntiles = (N + 15) / 16;                      // 6250

  hipMemsetAsync(bcnt, 0, 1024 * 4, stream);

  k_bhist     <<<nblk_e, 256, 0, stream>>>(ei, bcnt, E, nb);
  k_bscan     <<<1, 1024, 0, stream>>>(bcnt, bbase, bcur, nb, E);
  k_bscatter  <<<nblk_e, 256, 0, stream>>>(ei, bcur, ebuf, E, nb);
  k_bucket_csr<<<nb, 256, 0, stream>>>(ebuf, bbase, offs, csr, N, nb);
  k_agg1      <<<(N + 255) / 256, 256, 0, stream>>>(offs, csr, x, agg1, N);
  k_layer1    <<<((size_t)N * 64 + 255) / 256, 256, 0, stream>>>(x, agg1, offs, Wl1, Wr1, b1,
                                                                 (unsigned int*)h16, N);
  k_prepw     <<<(128 * 256) / 256, 256, 0, stream>>>(Wl2, Wr2, wt);
  k_agg2      <<<(N + 3) / 4, 256, 0, stream>>>(offs, csr, h16, (unsigned int*)a16, N);
  k_gemm      <<<((ntiles + 3) / 4) * 2, 256, 0, stream>>>(a16, h16, wt, b2, out, N);
}

// Round 5
// 274.337 us; speedup vs baseline: 1.6548x; 1.0115x over previous
//
#include <hip/hip_runtime.h>

// ---------------------------------------------------------------------------
// GraphSAGE 2-layer, mean aggregation.
//   L1: h = relu( mean_nbr(x) @ W_l1 + x @ W_r1 + b1 )   (IN=2 -> aggregate x first)
//   L2: out = mean_nbr(h) @ W_l2 + h @ W_r2 + b2
// R2: CSR via 2-level MSD binning (bucket = dst>>7).
// R3: k_gemm B staged in LDS (was latency-bound on serialized global B loads).
// R4: k_agg2 was co-limited (VALUBusy 48%, FETCH 177MB of 410MB logical):
//     gather h in fp8 e4m3 (128B/row, HW cvt_pk_f32_fp8 unpack) -> half bytes,
//     half table (better L2 hit), ~40% less VALU/value. a16 stays bf16.
//     Also: ebuf packed to 1 uint (src<<7|dst&127) -> halves scatter traffic.
// ---------------------------------------------------------------------------

using f32x4 = __attribute__((ext_vector_type(4))) float;
using f32x2 = __attribute__((ext_vector_type(2))) float;
using s16x8 = __attribute__((ext_vector_type(8))) short;

__device__ __forceinline__ unsigned short f32_to_bf16(float f) {
  unsigned int u = __float_as_uint(f);
  u += 0x7fffu + ((u >> 16) & 1u);          // round-to-nearest-even
  return (unsigned short)(u >> 16);
}

#define EDGE_TILE 4096

// ---- bin pass 1: bucket histogram (LDS-local, one global atomic/bucket) ----
__global__ __launch_bounds__(256) void k_bhist(const int* __restrict__ ei, int* __restrict__ bcnt,
                                               int E, int nb) {
  __shared__ int h[1024];
  int t = threadIdx.x;
  for (int i = t; i < nb; i += 256) h[i] = 0;
  __syncthreads();
  int tbeg = blockIdx.x * EDGE_TILE;
  int tend = min(tbeg + EDGE_TILE, E);
  const int* dstp = ei + E;
  for (int i = tbeg + t; i < tend; i += 256) atomicAdd(&h[dstp[i] >> 7], 1);
  __syncthreads();
  for (int i = t; i < nb; i += 256) if (h[i]) atomicAdd(&bcnt[i], h[i]);
}

// ---- bin pass 2: scan bucket counts -> bases + cursor copy ------------------
__global__ __launch_bounds__(1024) void k_bscan(const int* __restrict__ bcnt, int* __restrict__ bbase,
                                                int* __restrict__ bcur, int nb, int E) {
  __shared__ int sm[2][1024];
  int t = threadIdx.x;
  int v0 = (t < nb) ? bcnt[t] : 0;
  sm[0][t] = v0;
  __syncthreads();
  int src = 0;
  for (int st = 1; st < 1024; st <<= 1) {
    int v = sm[src][t];
    if (t >= st) v += sm[src][t - st];
    sm[src ^ 1][t] = v; __syncthreads(); src ^= 1;
  }
  int ex = sm[src][t] - v0;
  if (t < nb) { bbase[t] = ex; bcur[t] = ex; }
  if (t == 0) bbase[nb] = E;
}

// ---- bin pass 3: scatter packed (src<<7 | dst&127) into bucket-grouped ebuf -
__global__ __launch_bounds__(256) void k_bscatter(const int* __restrict__ ei, int* __restrict__ bcur,
                                                  unsigned int* __restrict__ ebuf, int E, int nb) {
  __shared__ int h[1024];
  __shared__ int base[1024];
  int t = threadIdx.x;
  for (int i = t; i < nb; i += 256) h[i] = 0;
  __syncthreads();
  int tbeg = blockIdx.x * EDGE_TILE;
  int tend = min(tbeg + EDGE_TILE, E);
  const int* srcp = ei;
  const int* dstp = ei + E;
  for (int i = tbeg + t; i < tend; i += 256) atomicAdd(&h[dstp[i] >> 7], 1);
  __syncthreads();
  for (int i = t; i < nb; i += 256) {
    int c = h[i];
    base[i] = c ? atomicAdd(&bcur[i], c) : 0;
    h[i] = 0;                                   // reuse as rank cursor
  }
  __syncthreads();
  for (int i = tbeg + t; i < tend; i += 256) {
    int d = dstp[i];
    int b = d >> 7;
    int r = atomicAdd(&h[b], 1);
    ebuf[base[b] + r] = ((unsigned)srcp[i] << 7) | (unsigned)(d & 127);
  }
}

// ---- bin pass 4: per-bucket local CSR build (offs + csr), block per bucket --
__global__ __launch_bounds__(256) void k_bucket_csr(const unsigned int* __restrict__ ebuf,
                                                    const int* __restrict__ bbase,
                                                    int* __restrict__ offs, int* __restrict__ csr,
                                                    int N, int nb) {
  __shared__ int deg[128];
  __shared__ int loff[128];
  __shared__ int cur[128];
  int b = blockIdx.x;
  int t = threadIdx.x;
  int lo = bbase[b], hi = bbase[b + 1];
  if (t < 128) deg[t] = 0;
  __syncthreads();
  for (int i = lo + t; i < hi; i += 256) atomicAdd(&deg[ebuf[i] & 127], 1);
  __syncthreads();
  if (t < 128) loff[t] = deg[t];
  __syncthreads();
  for (int st = 1; st < 128; st <<= 1) {
    int v = 0;
    if (t < 128 && t >= st) v = loff[t - st];
    __syncthreads();
    if (t < 128) loff[t] += v;
    __syncthreads();
  }
  if (t < 128) {
    int ex = loff[t] - deg[t];                 // exclusive prefix
    cur[t] = ex;
    int node = b * 128 + t;
    if (node < N) offs[node] = lo + ex;
  }
  if (b == nb - 1 && t == 0) offs[N] = hi;
  __syncthreads();
  for (int i = lo + t; i < hi; i += 256) {
    unsigned int e = ebuf[i];
    int r = atomicAdd(&cur[e & 127], 1);
    csr[lo + r] = (int)(e >> 7);
  }
}

// ---- layer-1 aggregation of x (2 dims), thread per node ---------------------
__global__ __launch_bounds__(256) void k_agg1(const int* __restrict__ offs, const int* __restrict__ csr,
                                              const float* __restrict__ x, float* __restrict__ agg1, int n) {
  int node = blockIdx.x * 256 + threadIdx.x;
  if (node >= n) return;
  int beg = offs[node], end = offs[node + 1];
  float s0 = 0.f, s1 = 0.f;
  const float2* x2 = (const float2*)x;
  for (int e = beg; e < end; ++e) {
    int s = csr[e];
    float2 v = x2[s];
    s0 += v.x; s1 += v.y;
  }
  agg1[2 * node] = s0; agg1[2 * node + 1] = s1;
}

// ---- layer-1 dense: h = relu(...), bf16 + fp8 out; 2 cols/thread ------------
__global__ __launch_bounds__(256) void k_layer1(const float* __restrict__ x, const float* __restrict__ agg1,
                                                const int* __restrict__ offs,
                                                const float* __restrict__ Wl, const float* __restrict__ Wr,
                                                const float* __restrict__ b1,
                                                unsigned int* __restrict__ h16,
                                                unsigned short* __restrict__ h8, int n) {
  int gid = blockIdx.x * 256 + threadIdx.x;
  int node = gid >> 6;
  if (node >= n) return;
  int c = (gid & 63) * 2;
  int deg = offs[node + 1] - offs[node];
  float sc = 1.0f / (float)max(deg, 1);
  float a0 = agg1[2 * node] * sc, a1 = agg1[2 * node + 1] * sc;
  float x0 = x[2 * node], x1 = x[2 * node + 1];
  float r0 = fmaf(a0, Wl[c],     fmaf(a1, Wl[128 + c],     fmaf(x0, Wr[c],     fmaf(x1, Wr[128 + c],     b1[c]))));
  float r1 = fmaf(a0, Wl[c + 1], fmaf(a1, Wl[128 + c + 1], fmaf(x0, Wr[c + 1], fmaf(x1, Wr[128 + c + 1], b1[c + 1]))));
  r0 = r0 > 0.f ? r0 : 0.f;
  r1 = r1 > 0.f ? r1 : 0.f;
  unsigned int packed = (unsigned int)f32_to_bf16(r0) | ((unsigned int)f32_to_bf16(r1) << 16);
  h16[(size_t)node * 64 + (gid & 63)] = packed;
  unsigned int p8 = (unsigned int)__builtin_amdgcn_cvt_pk_fp8_f32(r0, r1, 0, false);
  h8[(size_t)node * 64 + (gid & 63)] = (unsigned short)(p8 & 0xffffu);
}

// ---- prep: Wt[col][k] bf16, k<128 from W_l2, k>=128 from W_r2 ---------------
__global__ __launch_bounds__(256) void k_prepw(const float* __restrict__ Wl2, const float* __restrict__ Wr2,
                                               unsigned short* __restrict__ wt) {
  int tid = blockIdx.x * 256 + threadIdx.x;   // tid = c*256 + k
  if (tid >= 128 * 256) return;
  int c = tid >> 8, k = tid & 255;
  float v = (k < 128) ? Wl2[k * 128 + c] : Wr2[(k - 128) * 128 + c];
  wt[tid] = f32_to_bf16(v);
}

// ---- layer-2 aggregation: wave/node, 8 edges/iter, fp8 16B/lane gathers -----
__global__ __launch_bounds__(256) void k_agg2(const int* __restrict__ offs, const int* __restrict__ csr,
                                              const unsigned char* __restrict__ h8,
                                              unsigned int* __restrict__ a16, int n) {
  int node = blockIdx.x * 4 + (threadIdx.x >> 6);
  if (node >= n) return;
  int lane = threadIdx.x & 63;
  int g  = lane >> 3;        // edge subgroup 0..7
  int cb = lane & 7;         // col block: cols cb*16 .. cb*16+15
  int beg = offs[node], end = offs[node + 1];
  float acc[16];
#pragma unroll
  for (int j = 0; j < 16; ++j) acc[j] = 0.f;
  for (int e = beg; e < end; e += 8) {
    int idx = e + g;
    int cidx = idx < end ? idx : end - 1;     // end > beg inside loop
    float w = idx < end ? 1.f : 0.f;
    int s = csr[cidx];
    uint4 v = *(const uint4*)(h8 + (size_t)s * 128 + cb * 16);
    f32x2 p;
    p = __builtin_amdgcn_cvt_pk_f32_fp8((int)v.x, false); acc[0] = fmaf(w, p[0], acc[0]);  acc[1] = fmaf(w, p[1], acc[1]);
    p = __builtin_amdgcn_cvt_pk_f32_fp8((int)v.x, true);  acc[2] = fmaf(w, p[0], acc[2]);  acc[3] = fmaf(w, p[1], acc[3]);
    p = __builtin_amdgcn_cvt_pk_f32_fp8((int)v.y, false); acc[4] = fmaf(w, p[0], acc[4]);  acc[5] = fmaf(w, p[1], acc[5]);
    p = __builtin_amdgcn_cvt_pk_f32_fp8((int)v.y, true);  acc[6] = fmaf(w, p[0], acc[6]);  acc[7] = fmaf(w, p[1], acc[7]);
    p = __builtin_amdgcn_cvt_pk_f32_fp8((int)v.z, false); acc[8] = fmaf(w, p[0], acc[8]);  acc[9] = fmaf(w, p[1], acc[9]);
    p = __builtin_amdgcn_cvt_pk_f32_fp8((int)v.z, true);  acc[10] = fmaf(w, p[0], acc[10]); acc[11] = fmaf(w, p[1], acc[11]);
    p = __builtin_amdgcn_cvt_pk_f32_fp8((int)v.w, false); acc[12] = fmaf(w, p[0], acc[12]); acc[13] = fmaf(w, p[1], acc[13]);
    p = __builtin_amdgcn_cvt_pk_f32_fp8((int)v.w, true);  acc[14] = fmaf(w, p[0], acc[14]); acc[15] = fmaf(w, p[1], acc[15]);
  }
#pragma unroll
  for (int j = 0; j < 16; ++j) {
    acc[j] += __shfl_xor(acc[j], 8, 64);
    acc[j] += __shfl_xor(acc[j], 16, 64);
    acc[j] += __shfl_xor(acc[j], 32, 64);
  }
  if (g == 0) {            // lanes 0..7, cb = lane
    int deg = end - beg;
    float scale = 1.0f / (float)max(deg, 1);
    unsigned int u[8];
#pragma unroll
    for (int k = 0; k < 8; ++k)
      u[k] = (unsigned int)f32_to_bf16(acc[2 * k] * scale) |
             ((unsigned int)f32_to_bf16(acc[2 * k + 1] * scale) << 16);
    unsigned int* dst = a16 + (size_t)node * 64 + cb * 8;   // row = 64 uints
    *(uint4*)dst       = make_uint4(u[0], u[1], u[2], u[3]);
    *(uint4*)(dst + 4) = make_uint4(u[4], u[5], u[6], u[7]);
  }
}

// ---- layer-2 GEMM: out[N,128] = [agg2|h](bf16) @ Wt(bf16) + b2, MFMA --------
// Block: one column-half (64 cols) staged in LDS (row stride 264 shorts);
// 4 waves x one 16-row tile each.
__global__ __launch_bounds__(256) void k_gemm(const unsigned short* __restrict__ a16,
                                              const unsigned short* __restrict__ h16,
                                              const unsigned short* __restrict__ wt,
                                              const float* __restrict__ b2,
                                              float* __restrict__ out, int nrows) {
  __shared__ unsigned short bs[64 * 264];   // 33792 B
  int half = blockIdx.x & 1;
  int tg   = blockIdx.x >> 1;

#pragma unroll
  for (int i = 0; i < 8; ++i) {
    int c = threadIdx.x + i * 256;          // 0..2047
    int row = c >> 5, off = c & 31;         // off in 16B units
    *(uint4*)(bs + row * 264 + off * 8) =
        *(const uint4*)(wt + ((size_t)(half * 64 + row)) * 256 + off * 8);
  }
  __syncthreads();

  int wv   = threadIdx.x >> 6;
  int lane = threadIdx.x & 63;
  int m16 = lane & 15, quad = lane >> 4;
  int tile = tg * 4 + wv;
  if (tile * 16 >= nrows) return;

  int r  = tile * 16 + m16;
  int rc = r < nrows ? r : nrows - 1;
  const unsigned short* arow = a16 + (size_t)rc * 128 + quad * 8;
  const unsigned short* hrow = h16 + (size_t)rc * 128 + quad * 8;

  s16x8 afrag[8];
#pragma unroll
  for (int c4 = 0; c4 < 4; ++c4) {
    afrag[c4]     = *(const s16x8*)(arow + c4 * 32);   // A[m][k], k-chunk c4
    afrag[4 + c4] = *(const s16x8*)(hrow + c4 * 32);
  }

  f32x4 acc[4];
#pragma unroll
  for (int t = 0; t < 4; ++t) acc[t] = (f32x4){0.f, 0.f, 0.f, 0.f};

  const unsigned short* bbase = bs + m16 * 264 + quad * 8;
#pragma unroll
  for (int ch = 0; ch < 8; ++ch) {
#pragma unroll
    for (int t = 0; t < 4; ++t) {
      s16x8 bf = *(const s16x8*)(bbase + t * 16 * 264 + ch * 32); // B[k][n]
      acc[t] = __builtin_amdgcn_mfma_f32_16x16x32_bf16(afrag[ch], bf, acc[t], 0, 0, 0);
    }
  }

#pragma unroll
  for (int t = 0; t < 4; ++t) {
    int col = half * 64 + t * 16 + m16;
    float bias = b2[col];
#pragma unroll
    for (int i = 0; i < 4; ++i) {
      int row = tile * 16 + quad * 4 + i;   // C/D: col=lane&15, row=quad*4+reg
      if (row < nrows) out[(size_t)row * 128 + col] = acc[t][i] + bias;
    }
  }
}

// ---------------------------------------------------------------------------
extern "C" void kernel_launch(void* const* d_in, const int* in_sizes, int n_in,
                              void* d_out, int out_size, void* d_ws, size_t ws_size,
                              hipStream_t stream) {
  const float* x    = (const float*)d_in[0];
  const int*   ei   = (const int*)d_in[1];
  const float* Wl1  = (const float*)d_in[2];
  const float* Wr1  = (const float*)d_in[3];
  const float* b1   = (const float*)d_in[4];
  const float* Wl2  = (const float*)d_in[5];
  const float* Wr2  = (const float*)d_in[6];
  const float* b2   = (const float*)d_in[7];
  float* out = (float*)d_out;

  const int N = in_sizes[0] / 2;     // 100000
  const int E = in_sizes[1] / 2;     // 1600000
  const int nb = (N + 127) >> 7;     // 782 buckets

  // workspace carve-up (256B aligned)
  char* p = (char*)d_ws;
  auto take = [&](size_t bytes) { char* r = p; p += (bytes + 255) & ~(size_t)255; return r; };
  int* bcnt            = (int*)take(1024 * 4);
  int* bbase           = (int*)take(1025 * 4);
  int* bcur            = (int*)take(1024 * 4);
  int* offs            = (int*)take((size_t)(N + 1) * 4);
  int* csr             = (int*)take((size_t)E * 4);
  unsigned int* ebuf   = (unsigned int*)take((size_t)E * 4);
  float* agg1          = (float*)take((size_t)N * 2 * 4);
  unsigned short* h16  = (unsigned short*)take((size_t)N * 128 * 2);
  unsigned short* a16  = (unsigned short*)take((size_t)N * 128 * 2);
  unsigned short* h8   = (unsigned short*)take((size_t)N * 128);
  unsigned short* wt   = (unsigned short*)take((size_t)128 * 256 * 2);

  const int nblk_e = (E + EDGE_TILE - 1) / EDGE_TILE;   // 391
  const int ntiles = (N + 15) / 16;                      // 6250

  hipMemsetAsync(bcnt, 0, 1024 * 4, stream);

  k_bhist     <<<nblk_e, 256, 0, stream>>>(ei, bcnt, E, nb);
  k_bscan     <<<1, 1024, 0, stream>>>(bcnt, bbase, bcur, nb, E);
  k_bscatter  <<<nblk_e, 256, 0, stream>>>(ei, bcur, ebuf, E, nb);
  k_bucket_csr<<<nb, 256, 0, stream>>>(ebuf, bbase, offs, csr, N, nb);
  k_agg1      <<<(N + 255) / 256, 256, 0, stream>>>(offs, csr, x, agg1, N);
  k_layer1    <<<((size_t)N * 64 + 255) / 256, 256, 0, stream>>>(x, agg1, offs, Wl1, Wr1, b1,
                                                                 (unsigned int*)h16, h8, N);
  k_prepw     <<<(128 * 256) / 256, 256, 0, stream>>>(Wl2, Wr2, wt);
  k_agg2      <<<(N + 3) / 4, 256, 0, stream>>>(offs, csr, (const unsigned char*)h8,
                                                (unsigned int*)a16, N);
  k_gemm      <<<((ntiles + 3) / 4) * 2, 256, 0, stream>>>(a16, h16, wt, b2, out, N);
}